// Round 7
// baseline (147.301 us; speedup 1.0000x reference)
//
#include <hip/hip_runtime.h>
#include <math.h>

#define B_ 4096
#define D_ 256
#define C_ 64
#define BD (B_*D_)

__device__ __forceinline__ float wave_reduce_sum(float v) {
    #pragma unroll
    for (int off = 1; off < 64; off <<= 1) v += __shfl_xor(v, off);
    return v;
}

// full sum across each aligned 16-lane group, result in all 16 lanes (VALU-only DPP)
__device__ __forceinline__ float dpp_sum16(float v) {
    int t;
    t = __builtin_amdgcn_update_dpp(0, __float_as_int(v), 0x121, 0xF, 0xF, true); v += __int_as_float(t); // ror:1
    t = __builtin_amdgcn_update_dpp(0, __float_as_int(v), 0x122, 0xF, 0xF, true); v += __int_as_float(t); // ror:2
    t = __builtin_amdgcn_update_dpp(0, __float_as_int(v), 0x124, 0xF, 0xF, true); v += __int_as_float(t); // ror:4
    t = __builtin_amdgcn_update_dpp(0, __float_as_int(v), 0x128, 0xF, 0xF, true); v += __int_as_float(t); // ror:8
    return v;
}

// ---- single fused kernel: x-copy stripe + Sum(x^2) partial, local bucket scan,
//      W-L1 partial (sl==0), grouped matvec, then counter-gated in-place
//      normalize (last ot-block of each (cond,sl) group) and scalar finalize
//      (last block overall).  grid = 64 conds x 4 ot x 4 sl = 1024 ----
__global__ __launch_bounds__(256) void k_main(const float* __restrict__ W,
                                              const float* __restrict__ b,
                                              const float* __restrict__ x,
                                              const int* __restrict__ c,
                                              float* __restrict__ out,
                                              float* __restrict__ l1p,
                                              float* __restrict__ xsqp,
                                              int* __restrict__ cnt4,
                                              int* __restrict__ done) {
    int hw = blockIdx.x;
    int bid = (hw & 7) * 128 + (hw >> 3);   // XCD swizzle: 128 consecutive logical blocks per XCD
    int cond = bid >> 4;
    int ot = (bid >> 2) & 3;
    int sl = bid & 3;
    int tid = threadIdx.x;
    int rg = tid >> 4, kseg = tid & 15;
    int swz = kseg >> 1;
    int row0 = ot * 64 + rg * 4;

    // --- issue independent loads early: W strip, x-copy stripe, c scan ---
    float4 Wreg[4][4];
    #pragma unroll
    for (int rr = 0; rr < 4; ++rr) {
        const float4* wp = (const float4*)(W + (size_t)cond * (D_ * D_) + (size_t)(row0 + rr) * D_ + kseg * 16);
        #pragma unroll
        for (int j = 0; j < 4; ++j) Wreg[rr][j] = wp[j];
    }
    int xi = bid * 256 + tid;                       // float4 index into x (262144 total / 1024 blocks)
    float4 xv = ((const float4*)x)[xi];
    int4 cv[4];
    #pragma unroll
    for (int t = 0; t < 4; ++t) cv[t] = ((const int4*)c)[tid + 256 * t];

    #pragma unroll
    for (int rr = 0; rr < 4; ++rr)
        #pragma unroll
        for (int j = 0; j < 4; ++j)
            asm volatile("" : "+v"(Wreg[rr][j].x), "+v"(Wreg[rr][j].y), "+v"(Wreg[rr][j].z), "+v"(Wreg[rr][j].w));

    __shared__ float part_x[4];
    __shared__ float part_w[4];
    __shared__ int slist[1024];
    __shared__ int nlist;
    __shared__ int winner;
    if (tid == 0) nlist = 0;

    // x copy to out tail + sumsq partial
    float2* dst = (float2*)(out + BD + 2);
    dst[2 * xi]     = make_float2(xv.x, xv.y);
    dst[2 * xi + 1] = make_float2(xv.z, xv.w);
    float s = xv.x * xv.x + xv.y * xv.y + xv.z * xv.z + xv.w * xv.w;
    s = wave_reduce_sum(s);
    int wid = tid >> 6, lane = tid & 63;
    if (lane == 0) part_x[wid] = s;

    // |W| L1 partial (only sl==0 blocks: W counted exactly once overall)
    if (sl == 0) {
        float a = 0.f;
        #pragma unroll
        for (int rr = 0; rr < 4; ++rr)
            #pragma unroll
            for (int j = 0; j < 4; ++j)
                a += fabsf(Wreg[rr][j].x) + fabsf(Wreg[rr][j].y) + fabsf(Wreg[rr][j].z) + fabsf(Wreg[rr][j].w);
        a = wave_reduce_sum(a);
        if (lane == 0) part_w[wid] = a;
    }
    __syncthreads();
    if (tid == 0) {
        xsqp[bid] = (part_x[0] + part_x[1]) + (part_x[2] + part_x[3]);
        if (sl == 0) l1p[cond * 4 + ot] = (part_w[0] + part_w[1]) + (part_w[2] + part_w[3]);
    }

    // local bucket scan: slice sl owns samples i == sl (mod 4); int4 component sl
    #pragma unroll
    for (int t = 0; t < 4; ++t) {
        int4 q = cv[t];
        int cc = (sl == 0) ? q.x : (sl == 1) ? q.y : (sl == 2) ? q.z : q.w;
        if (cc == cond) {
            int pos = atomicAdd(&nlist, 1);
            slist[pos] = 4 * (tid + 256 * t) + sl;
        }
    }
    __syncthreads();
    int n = nlist;
    if (ot == 0 && tid == 0) cnt4[cond * 4 + sl] = n;

    float4 bias = ((const float4*)(b + cond * D_ + ot * 64))[rg];

    __shared__ float4 xs[16 * 64];
    for (int s0 = 0; s0 < n; s0 += 16) {
        int ns = min(16, n - s0);
        __syncthreads();
        for (int u = tid; u < ns * 64; u += 256) {
            int si = u >> 6, v = u & 63;
            int sg = slist[s0 + si];
            xs[si * 64 + (v & 0x3C) + (((v & 3) + (v >> 3)) & 3)] = ((const float4*)x)[(size_t)sg * 64 + v];
        }
        __syncthreads();
        for (int si = 0; si < ns; ++si) {
            const float4* xp = &xs[si * 64 + kseg * 4];
            float4 a0 = make_float4(0.f, 0.f, 0.f, 0.f);
            float4 a1 = a0, a2 = a0, a3 = a0;
            #pragma unroll
            for (int jl = 0; jl < 4; ++jl) {
                float4 q = xp[(jl + swz) & 3];
                a0.x += Wreg[0][jl].x * q.x; a0.y += Wreg[0][jl].y * q.y;
                a0.z += Wreg[0][jl].z * q.z; a0.w += Wreg[0][jl].w * q.w;
                a1.x += Wreg[1][jl].x * q.x; a1.y += Wreg[1][jl].y * q.y;
                a1.z += Wreg[1][jl].z * q.z; a1.w += Wreg[1][jl].w * q.w;
                a2.x += Wreg[2][jl].x * q.x; a2.y += Wreg[2][jl].y * q.y;
                a2.z += Wreg[2][jl].z * q.z; a2.w += Wreg[2][jl].w * q.w;
                a3.x += Wreg[3][jl].x * q.x; a3.y += Wreg[3][jl].y * q.y;
                a3.z += Wreg[3][jl].z * q.z; a3.w += Wreg[3][jl].w * q.w;
            }
            float r0 = dpp_sum16((a0.x + a0.y) + (a0.z + a0.w));
            float r1 = dpp_sum16((a1.x + a1.y) + (a1.z + a1.w));
            float r2 = dpp_sum16((a2.x + a2.y) + (a2.z + a2.w));
            float r3 = dpp_sum16((a3.x + a3.y) + (a3.z + a3.w));
            if (kseg == 0) {
                int sg = slist[s0 + si];
                ((float4*)out)[(size_t)sg * 64 + ot * 16 + rg] =
                    make_float4(r0 + bias.x, r1 + bias.y, r2 + bias.z, r3 + bias.w);
            }
        }
    }

    // ---- fused epilogue: counter-gated normalize + scalar finalize ----
    __syncthreads();                 // all lanes' y-stores issued
    __threadfence();                 // release this thread's writes (device scope)
    __syncthreads();
    if (tid == 0) {
        int w = 0;
        int old = __hip_atomic_fetch_add(&done[cond * 4 + sl], 1,
                                         __ATOMIC_ACQ_REL, __HIP_MEMORY_SCOPE_AGENT);
        if (old == 3) w |= 1;        // last ot-block of this (cond,sl) group
        int g = __hip_atomic_fetch_add(&done[256], 1,
                                       __ATOMIC_ACQ_REL, __HIP_MEMORY_SCOPE_AGENT);
        if (g == 1023) w |= 2;       // last block overall
        winner = w;
    }
    __syncthreads();

    if (winner & 1) {                // normalize this group's n sample rows in place
        float4* yp = (float4*)out;
        for (int si = wid; si < n; si += 4) {
            int sg = slist[si];
            float4 v = yp[(size_t)sg * 64 + lane];
            float s2 = v.x * v.x + v.y * v.y + v.z * v.z + v.w * v.w;
            s2 = wave_reduce_sum(s2);
            float inv = 1.0f / fmaxf(sqrtf(s2), 1e-10f);
            v.x *= inv; v.y *= inv; v.z *= inv; v.w *= inv;
            yp[(size_t)sg * 64 + lane] = v;
        }
    }
    if (winner & 2) {                // finalize embed_norm + mask_norm
        __shared__ float part2[4];
        float s2 = 0.f;
        #pragma unroll
        for (int j = 0; j < 4; ++j) s2 += xsqp[tid * 4 + j];
        s2 = wave_reduce_sum(s2);
        if (lane == 0) part2[wid] = s2;
        __syncthreads();
        if (tid < 64) {
            float l1 = (l1p[tid * 4 + 0] + l1p[tid * 4 + 1]) + (l1p[tid * 4 + 2] + l1p[tid * 4 + 3]);
            float cnt = (float)((cnt4[tid * 4 + 0] + cnt4[tid * 4 + 1]) + (cnt4[tid * 4 + 2] + cnt4[tid * 4 + 3]));
            float mv = l1 * cnt;
            mv = wave_reduce_sum(mv);
            if (tid == 0) out[BD] = mv;                                                // mask_norm
        }
        if (tid == 0) out[BD + 1] = sqrtf((part2[0] + part2[1]) + (part2[2] + part2[3])); // embed_norm
    }
}

extern "C" void kernel_launch(void* const* d_in, const int* in_sizes, int n_in,
                              void* d_out, int out_size, void* d_ws, size_t ws_size,
                              hipStream_t stream) {
    const float* x = (const float*)d_in[0];
    const float* W = (const float*)d_in[1];
    const float* b = (const float*)d_in[2];
    const int*   c = (const int*)d_in[3];
    float* out = (float*)d_out;

    float* xsqp = (float*)d_ws;           // 1024
    float* l1p  = xsqp + 1024;            // 256
    int*   cnt4 = (int*)(l1p + 256);      // 256
    int*   done = cnt4 + 256;             // 256 group counters + 1 global ticket

    hipMemsetAsync(done, 0, 257 * sizeof(int), stream);
    k_main<<<1024, 256, 0, stream>>>(W, b, x, c, out, l1p, xsqp, cnt4, done);
}

// Round 8
// 28.602 us; speedup vs baseline: 5.1500x; 5.1500x over previous
//
#include <hip/hip_runtime.h>
#include <math.h>

#define B_ 4096
#define D_ 256
#define C_ 64
#define BD (B_*D_)

__device__ __forceinline__ float wave_reduce_sum(float v) {
    #pragma unroll
    for (int off = 1; off < 64; off <<= 1) v += __shfl_xor(v, off);
    return v;
}

// full sum across each aligned 16-lane group, result in all 16 lanes (VALU-only DPP)
__device__ __forceinline__ float dpp_sum16(float v) {
    int t;
    t = __builtin_amdgcn_update_dpp(0, __float_as_int(v), 0x121, 0xF, 0xF, true); v += __int_as_float(t); // ror:1
    t = __builtin_amdgcn_update_dpp(0, __float_as_int(v), 0x122, 0xF, 0xF, true); v += __int_as_float(t); // ror:2
    t = __builtin_amdgcn_update_dpp(0, __float_as_int(v), 0x124, 0xF, 0xF, true); v += __int_as_float(t); // ror:4
    t = __builtin_amdgcn_update_dpp(0, __float_as_int(v), 0x128, 0xF, 0xF, true); v += __int_as_float(t); // ror:8
    return v;
}

// ---- fused: per-block x-copy stripe + Sum(x^2) partial, local bucket scan,
//      W-L1 partial (sl==0), grouped matvec (32-sample tiles: ~1 tile/block).
//      grid = 64 conds x 4 ot x 4 sl ----
__global__ __launch_bounds__(256) void k_main(const float* __restrict__ W,
                                              const float* __restrict__ b,
                                              const float* __restrict__ x,
                                              const int* __restrict__ c,
                                              float* __restrict__ out,
                                              float* __restrict__ l1p,
                                              float* __restrict__ xsqp,
                                              int* __restrict__ cnt4) {
    int hw = blockIdx.x;
    int bid = (hw & 7) * 128 + (hw >> 3);   // XCD swizzle: 128 consecutive logical blocks per XCD
    int cond = bid >> 4;
    int ot = (bid >> 2) & 3;
    int sl = bid & 3;
    int tid = threadIdx.x;
    int rg = tid >> 4, kseg = tid & 15;
    int swz = kseg >> 1;
    int row0 = ot * 64 + rg * 4;

    // --- issue independent loads early: W strip, x-copy stripe, c scan ---
    float4 Wreg[4][4];
    #pragma unroll
    for (int rr = 0; rr < 4; ++rr) {
        const float4* wp = (const float4*)(W + (size_t)cond * (D_ * D_) + (size_t)(row0 + rr) * D_ + kseg * 16);
        #pragma unroll
        for (int j = 0; j < 4; ++j) Wreg[rr][j] = wp[j];
    }
    int xi = bid * 256 + tid;                       // float4 index into x (262144 total / 1024 blocks)
    float4 xv = ((const float4*)x)[xi];
    int4 cv[4];
    #pragma unroll
    for (int t = 0; t < 4; ++t) cv[t] = ((const int4*)c)[tid + 256 * t];

    #pragma unroll
    for (int rr = 0; rr < 4; ++rr)
        #pragma unroll
        for (int j = 0; j < 4; ++j)
            asm volatile("" : "+v"(Wreg[rr][j].x), "+v"(Wreg[rr][j].y), "+v"(Wreg[rr][j].z), "+v"(Wreg[rr][j].w));

    __shared__ float part_x[4];
    __shared__ float part_w[4];
    __shared__ int slist[1024];
    __shared__ int nlist;
    if (tid == 0) nlist = 0;

    // x copy to out tail + sumsq partial
    float2* dst = (float2*)(out + BD + 2);
    dst[2 * xi]     = make_float2(xv.x, xv.y);
    dst[2 * xi + 1] = make_float2(xv.z, xv.w);
    float s = xv.x * xv.x + xv.y * xv.y + xv.z * xv.z + xv.w * xv.w;
    s = wave_reduce_sum(s);
    int wid = tid >> 6, lane = tid & 63;
    if (lane == 0) part_x[wid] = s;

    // |W| L1 partial (only sl==0 blocks: W counted exactly once overall)
    if (sl == 0) {
        float a = 0.f;
        #pragma unroll
        for (int rr = 0; rr < 4; ++rr)
            #pragma unroll
            for (int j = 0; j < 4; ++j)
                a += fabsf(Wreg[rr][j].x) + fabsf(Wreg[rr][j].y) + fabsf(Wreg[rr][j].z) + fabsf(Wreg[rr][j].w);
        a = wave_reduce_sum(a);
        if (lane == 0) part_w[wid] = a;
    }
    __syncthreads();
    if (tid == 0) {
        xsqp[bid] = (part_x[0] + part_x[1]) + (part_x[2] + part_x[3]);
        if (sl == 0) l1p[cond * 4 + ot] = (part_w[0] + part_w[1]) + (part_w[2] + part_w[3]);
    }

    // local bucket scan: slice sl owns samples i == sl (mod 4); int4 component sl
    #pragma unroll
    for (int t = 0; t < 4; ++t) {
        int4 q = cv[t];
        int cc = (sl == 0) ? q.x : (sl == 1) ? q.y : (sl == 2) ? q.z : q.w;
        if (cc == cond) {
            int pos = atomicAdd(&nlist, 1);
            slist[pos] = 4 * (tid + 256 * t) + sl;
        }
    }
    __syncthreads();
    int n = nlist;
    if (ot == 0 && tid == 0) cnt4[cond * 4 + sl] = n;

    float4 bias = ((const float4*)(b + cond * D_ + ot * 64))[rg];

    __shared__ float4 xs[32 * 64];          // 32-sample tile: ~all blocks run 1 tile
    for (int s0 = 0; s0 < n; s0 += 32) {
        int ns = min(32, n - s0);
        __syncthreads();
        for (int u = tid; u < ns * 64; u += 256) {
            int si = u >> 6, v = u & 63;
            int sg = slist[s0 + si];
            xs[si * 64 + (v & 0x3C) + (((v & 3) + (v >> 3)) & 3)] = ((const float4*)x)[(size_t)sg * 64 + v];
        }
        __syncthreads();
        for (int si = 0; si < ns; ++si) {
            const float4* xp = &xs[si * 64 + kseg * 4];
            float4 a0 = make_float4(0.f, 0.f, 0.f, 0.f);
            float4 a1 = a0, a2 = a0, a3 = a0;
            #pragma unroll
            for (int jl = 0; jl < 4; ++jl) {
                float4 q = xp[(jl + swz) & 3];
                a0.x += Wreg[0][jl].x * q.x; a0.y += Wreg[0][jl].y * q.y;
                a0.z += Wreg[0][jl].z * q.z; a0.w += Wreg[0][jl].w * q.w;
                a1.x += Wreg[1][jl].x * q.x; a1.y += Wreg[1][jl].y * q.y;
                a1.z += Wreg[1][jl].z * q.z; a1.w += Wreg[1][jl].w * q.w;
                a2.x += Wreg[2][jl].x * q.x; a2.y += Wreg[2][jl].y * q.y;
                a2.z += Wreg[2][jl].z * q.z; a2.w += Wreg[2][jl].w * q.w;
                a3.x += Wreg[3][jl].x * q.x; a3.y += Wreg[3][jl].y * q.y;
                a3.z += Wreg[3][jl].z * q.z; a3.w += Wreg[3][jl].w * q.w;
            }
            float r0 = dpp_sum16((a0.x + a0.y) + (a0.z + a0.w));
            float r1 = dpp_sum16((a1.x + a1.y) + (a1.z + a1.w));
            float r2 = dpp_sum16((a2.x + a2.y) + (a2.z + a2.w));
            float r3 = dpp_sum16((a3.x + a3.y) + (a3.z + a3.w));
            if (kseg == 0) {
                int sg = slist[s0 + si];
                ((float4*)out)[(size_t)sg * 64 + ot * 16 + rg] =
                    make_float4(r0 + bias.x, r1 + bias.y, r2 + bias.z, r3 + bias.w);
            }
        }
    }
}

// ---- blocks 0..1023: in-place row L2-normalize ----
// ---- block 1024: finalize embed_norm (xsqp) and mask_norm (l1p, cnt4) ----
__global__ __launch_bounds__(256) void k_finish(float* __restrict__ out,
                                                const float* __restrict__ xsqp,
                                                const float* __restrict__ l1p,
                                                const int* __restrict__ cnt4) {
    int tid = threadIdx.x;
    if (blockIdx.x == 1024) {
        __shared__ float part[4];
        float s = 0.f;
        #pragma unroll
        for (int j = 0; j < 4; ++j) s += xsqp[tid * 4 + j];
        s = wave_reduce_sum(s);
        int wid = tid >> 6, lane = tid & 63;
        if (lane == 0) part[wid] = s;
        __syncthreads();
        if (tid < 64) {
            float l1 = (l1p[tid * 4 + 0] + l1p[tid * 4 + 1]) + (l1p[tid * 4 + 2] + l1p[tid * 4 + 3]);
            float cnt = (float)((cnt4[tid * 4 + 0] + cnt4[tid * 4 + 1]) + (cnt4[tid * 4 + 2] + cnt4[tid * 4 + 3]));
            float mv = l1 * cnt;
            mv = wave_reduce_sum(mv);
            if (tid == 0) out[BD] = mv;                                               // mask_norm
        }
        if (tid == 0) out[BD + 1] = sqrtf((part[0] + part[1]) + (part[2] + part[3])); // embed_norm
        return;
    }
    int rowv = blockIdx.x * 4 + (tid >> 6);   // 4096 rows, wave per row
    int lane = tid & 63;
    float4* p = (float4*)out + (size_t)rowv * 64 + lane;
    float4 v = *p;
    float s = v.x * v.x + v.y * v.y + v.z * v.z + v.w * v.w;
    s = wave_reduce_sum(s);
    float inv = 1.0f / fmaxf(sqrtf(s), 1e-10f);
    v.x *= inv; v.y *= inv; v.z *= inv; v.w *= inv;
    *p = v;
}

extern "C" void kernel_launch(void* const* d_in, const int* in_sizes, int n_in,
                              void* d_out, int out_size, void* d_ws, size_t ws_size,
                              hipStream_t stream) {
    const float* x = (const float*)d_in[0];
    const float* W = (const float*)d_in[1];
    const float* b = (const float*)d_in[2];
    const int*   c = (const int*)d_in[3];
    float* out = (float*)d_out;

    float* xsqp = (float*)d_ws;           // 1024
    float* l1p  = xsqp + 1024;            // 256
    int*   cnt4 = (int*)(l1p + 256);      // 256

    k_main<<<1024, 256, 0, stream>>>(W, b, x, c, out, l1p, xsqp, cnt4);
    k_finish<<<1025, 256, 0, stream>>>(out, xsqp, l1p, cnt4);
}